// Round 9
// baseline (14.060 us; speedup 1.0000x reference)
//
#include <hip/hip_runtime.h>

#define NN 128

typedef __attribute__((ext_vector_type(8))) short short8;
typedef __attribute__((ext_vector_type(4))) float f32x4;

__device__ __forceinline__ unsigned asu(float x) { return __float_as_uint(x); }
__device__ __forceinline__ float asf(unsigned u) { return __uint_as_float(u); }

// pack 2 floats -> one word of 2 bf16 (truncation)
__device__ __forceinline__ unsigned pk_hi(float v0, float v1) {
    return (asu(v0) >> 16) | (asu(v1) & 0xffff0000u);
}
// truncation residual: x - bf16_trunc(x)
__device__ __forceinline__ float resid(float x) {
    return x - asf(asu(x) & 0xffff0000u);
}

// LDS-light (9 KB) fused GAT attention — no A staging, B-fragments from global.
// grid = 512: t = bid & 63 (i-blocks of one t share an XCD -> A[t] L2-resident),
// ib = bid >> 6 (16 output rows). block = 256 (4 waves, 32 f-cols per wave).
// Occupancy: VGPR-bound, target 4 blocks/CU (16 waves/CU).
__global__ __launch_bounds__(256, 4) void gat_fused(
    const float* __restrict__ A, const float* __restrict__ W,
    const float* __restrict__ b, float* __restrict__ out)
{
    __shared__ float part1_s[4 * NN];   // per-wave s1 partials (2 KB)
    __shared__ float part2_s[4 * NN];   // per-wave s2 partials (2 KB)
    __shared__ float s1_s[NN], s2_s[NN];

    const int tid  = threadIdx.x;
    const int lane = tid & 63;
    const int wid  = tid >> 6;
    const int t    = blockIdx.x & 63;
    const int i0   = (blockIdx.x >> 6) << 4;
    const float* At = A + (size_t)t * NN * NN;

    // ---- phase 1: streaming s1/s2 partials (coalesced, no staging) ----
    {
        const float4* A4 = reinterpret_cast<const float4*>(At);
        float p1[4] = {0,0,0,0}, p2[4] = {0,0,0,0};
        #pragma unroll
        for (int it = 0; it < 16; ++it) {
            int e4 = it * 256 + tid;          // float4 index 0..4095, coalesced
            int f  = e4 >> 5;                 // A row = reduction index k
            float4 v = A4[e4];
            float w1 = W[f], w2 = W[NN + f];  // wave-uniform broadcast loads
            p1[0] += w1 * v.x; p1[1] += w1 * v.y; p1[2] += w1 * v.z; p1[3] += w1 * v.w;
            p2[0] += w2 * v.x; p2[1] += w2 * v.y; p2[2] += w2 * v.z; p2[3] += w2 * v.w;
        }
        // lane l and l^32 covered disjoint row sets of the same columns
        #pragma unroll
        for (int q = 0; q < 4; ++q) {
            p1[q] += __shfl_xor(p1[q], 32);
            p2[q] += __shfl_xor(p2[q], 32);
        }
        if (lane < 32) {                      // col = lane*4+q
            float4 v1 = { p1[0], p1[1], p1[2], p1[3] };
            float4 v2 = { p2[0], p2[1], p2[2], p2[3] };
            *reinterpret_cast<float4*>(&part1_s[wid * NN + lane * 4]) = v1;
            *reinterpret_cast<float4*>(&part2_s[wid * NN + lane * 4]) = v2;
        }
    }
    __syncthreads();

    const int f0 = wid << 5;                  // wave's 32 output cols
    const int r  = lane & 15;
    const int g  = lane >> 4;                 // k sub-group 0..3
    const int kg = g << 3;

    // ---- issue the wave's B-row reads now (L2-hot); latency hides under
    //      s-reduce + softmax. B[j,f]=A[t,f,j]: lane holds rows f0+r, f0+16+r.
    const float* Brow0 = At + (size_t)(f0 + r) * NN + kg;
    const float* Brow1 = At + (size_t)(f0 + 16 + r) * NN + kg;
    float4 bv0[8], bv1[8];
    #pragma unroll
    for (int k = 0; k < 4; ++k) {
        bv0[2 * k]     = *reinterpret_cast<const float4*>(Brow0 + 32 * k);
        bv0[2 * k + 1] = *reinterpret_cast<const float4*>(Brow0 + 32 * k + 4);
        bv1[2 * k]     = *reinterpret_cast<const float4*>(Brow1 + 32 * k);
        bv1[2 * k + 1] = *reinterpret_cast<const float4*>(Brow1 + 32 * k + 4);
    }

    // ---- final s1/s2 reduce (wave-uniform branch: waves 0-1 vs 2-3) ----
    if (tid < NN) {
        s1_s[tid] = part1_s[tid] + part1_s[NN + tid]
                  + part1_s[2 * NN + tid] + part1_s[3 * NN + tid] + b[0];
    } else {
        int c = tid - NN;
        s2_s[c] = part2_s[c] + part2_s[NN + c]
                + part2_s[2 * NN + c] + part2_s[3 * NN + c];
    }
    __syncthreads();

    // ---- 3-sweep register softmax for row i0+r over this lane's 32 cols ----
    // (cols k0*32 + kg + e). Row group = lanes {r, r+16, r+32, r+48}.
    const float s1v = s1_s[i0 + r];
    float m = -3.4e38f;
    #pragma unroll
    for (int k0 = 0; k0 < 4; ++k0) {
        float4 sa = *reinterpret_cast<const float4*>(&s2_s[k0 * 32 + kg]);
        float4 sb = *reinterpret_cast<const float4*>(&s2_s[k0 * 32 + kg + 4]);
        float xs[8] = { sa.x, sa.y, sa.z, sa.w, sb.x, sb.y, sb.z, sb.w };
        #pragma unroll
        for (int e = 0; e < 8; ++e) {
            float x = s1v + xs[e];
            x = (x >= 0.f) ? x : 0.2f * x;    // leaky_relu 0.2
            m = fmaxf(m, x);
        }
    }
    m = fmaxf(m, __shfl_xor(m, 16));
    m = fmaxf(m, __shfl_xor(m, 32));
    float s = 0.f;
    #pragma unroll
    for (int k0 = 0; k0 < 4; ++k0) {
        float4 sa = *reinterpret_cast<const float4*>(&s2_s[k0 * 32 + kg]);
        float4 sb = *reinterpret_cast<const float4*>(&s2_s[k0 * 32 + kg + 4]);
        float xs[8] = { sa.x, sa.y, sa.z, sa.w, sb.x, sb.y, sb.z, sb.w };
        #pragma unroll
        for (int e = 0; e < 8; ++e) {
            float x = s1v + xs[e];
            x = (x >= 0.f) ? x : 0.2f * x;
            s += __expf(x - m);
        }
    }
    s += __shfl_xor(s, 16);
    s += __shfl_xor(s, 32);
    const float ls = m + __logf(s);           // alpha = exp(x - ls)

    // ---- pack B hi/lo fragments (frees bv) ----
    short8 bh0[4], bh1[4], bl0[4], bl1[4];
    #pragma unroll
    for (int k = 0; k < 4; ++k) {
        union { short8 s8; unsigned u[4]; } H0, L0, H1, L1;
        H0.u[0] = pk_hi(bv0[2 * k].x, bv0[2 * k].y);
        H0.u[1] = pk_hi(bv0[2 * k].z, bv0[2 * k].w);
        H0.u[2] = pk_hi(bv0[2 * k + 1].x, bv0[2 * k + 1].y);
        H0.u[3] = pk_hi(bv0[2 * k + 1].z, bv0[2 * k + 1].w);
        L0.u[0] = pk_hi(resid(bv0[2 * k].x),     resid(bv0[2 * k].y));
        L0.u[1] = pk_hi(resid(bv0[2 * k].z),     resid(bv0[2 * k].w));
        L0.u[2] = pk_hi(resid(bv0[2 * k + 1].x), resid(bv0[2 * k + 1].y));
        L0.u[3] = pk_hi(resid(bv0[2 * k + 1].z), resid(bv0[2 * k + 1].w));
        H1.u[0] = pk_hi(bv1[2 * k].x, bv1[2 * k].y);
        H1.u[1] = pk_hi(bv1[2 * k].z, bv1[2 * k].w);
        H1.u[2] = pk_hi(bv1[2 * k + 1].x, bv1[2 * k + 1].y);
        H1.u[3] = pk_hi(bv1[2 * k + 1].z, bv1[2 * k + 1].w);
        L1.u[0] = pk_hi(resid(bv1[2 * k].x),     resid(bv1[2 * k].y));
        L1.u[1] = pk_hi(resid(bv1[2 * k].z),     resid(bv1[2 * k].w));
        L1.u[2] = pk_hi(resid(bv1[2 * k + 1].x), resid(bv1[2 * k + 1].y));
        L1.u[3] = pk_hi(resid(bv1[2 * k + 1].z), resid(bv1[2 * k + 1].w));
        bh0[k] = H0.s8; bl0[k] = L0.s8;
        bh1[k] = H1.s8; bl1[k] = L1.s8;
    }

    // ---- pack sweep: alpha -> hi/lo bf16 A-fragments ----
    short8 ah[4], al[4];
    #pragma unroll
    for (int k0 = 0; k0 < 4; ++k0) {
        float4 sa = *reinterpret_cast<const float4*>(&s2_s[k0 * 32 + kg]);
        float4 sb = *reinterpret_cast<const float4*>(&s2_s[k0 * 32 + kg + 4]);
        float xs[8] = { sa.x, sa.y, sa.z, sa.w, sb.x, sb.y, sb.z, sb.w };
        float av[8];
        #pragma unroll
        for (int e = 0; e < 8; ++e) {
            float x = s1v + xs[e];
            x = (x >= 0.f) ? x : 0.2f * x;
            av[e] = __expf(x - ls);
        }
        union { short8 s8; unsigned u[4]; } H, L;
        #pragma unroll
        for (int p = 0; p < 4; ++p) {
            H.u[p] = pk_hi(av[2 * p], av[2 * p + 1]);
            L.u[p] = pk_hi(resid(av[2 * p]), resid(av[2 * p + 1]));
        }
        ah[k0] = H.s8; al[k0] = L.s8;
    }

    // ---- MFMA: ah*bh + al*bh + ah*bl (two independent acc chains) ----
    f32x4 acc0 = {0.f,0.f,0.f,0.f}, acc1 = {0.f,0.f,0.f,0.f};
    #pragma unroll
    for (int k0 = 0; k0 < 4; ++k0) {
        acc0 = __builtin_amdgcn_mfma_f32_16x16x32_bf16(ah[k0], bh0[k0], acc0, 0, 0, 0);
        acc1 = __builtin_amdgcn_mfma_f32_16x16x32_bf16(ah[k0], bh1[k0], acc1, 0, 0, 0);
    }
    #pragma unroll
    for (int k0 = 0; k0 < 4; ++k0) {
        acc0 = __builtin_amdgcn_mfma_f32_16x16x32_bf16(al[k0], bh0[k0], acc0, 0, 0, 0);
        acc1 = __builtin_amdgcn_mfma_f32_16x16x32_bf16(al[k0], bh1[k0], acc1, 0, 0, 0);
    }
    #pragma unroll
    for (int k0 = 0; k0 < 4; ++k0) {
        acc0 = __builtin_amdgcn_mfma_f32_16x16x32_bf16(ah[k0], bl0[k0], acc0, 0, 0, 0);
        acc1 = __builtin_amdgcn_mfma_f32_16x16x32_bf16(ah[k0], bl1[k0], acc1, 0, 0, 0);
    }

    // C/D: col = lane&15 (f), row = g*4 + q (i)
    float* outt = out + (size_t)t * NN * NN + (size_t)(i0 + (g << 2)) * NN;
    #pragma unroll
    for (int q = 0; q < 4; ++q) {
        outt[q * NN + f0 + r]      = acc0[q];
        outt[q * NN + f0 + 16 + r] = acc1[q];
    }
}

extern "C" void kernel_launch(void* const* d_in, const int* in_sizes, int n_in,
                              void* d_out, int out_size, void* d_ws, size_t ws_size,
                              hipStream_t stream) {
    const float* A = (const float*)d_in[0];
    const float* W = (const float*)d_in[1];
    const float* b = (const float*)d_in[2];
    float* out = (float*)d_out;
    gat_fused<<<dim3(512), dim3(256), 0, stream>>>(A, W, b, out);
}

// Round 10
// 10.210 us; speedup vs baseline: 1.3771x; 1.3771x over previous
//
#include <hip/hip_runtime.h>

#define NN 128

typedef __attribute__((ext_vector_type(8))) short short8;
typedef __attribute__((ext_vector_type(4))) float f32x4;

// XOR-swizzled LDS index (units = shorts) for row-major [rows][128] bf16.
// Flips the 16B granule by row&7 -> column-slice ds_read_b128 across 16 rows
// hits all 32 banks at 2-way max (free). Bits <3 untouched -> 8/16B alignment kept.
__device__ __forceinline__ int SWZ(int r, int cs) {
    return (r << 7) + (cs ^ ((r & 7) << 3));
}

__device__ __forceinline__ unsigned asu(float x) { return __float_as_uint(x); }
__device__ __forceinline__ float asf(unsigned u) { return __uint_as_float(u); }

// pack 2 floats -> one word of 2 bf16 (truncation)
__device__ __forceinline__ unsigned pk_hi(float v0, float v1) {
    return (asu(v0) >> 16) | (asu(v1) & 0xffff0000u);
}
// truncation residual: x - bf16_trunc(x)
__device__ __forceinline__ float resid(float x) {
    return x - asf(asu(x) & 0xffff0000u);
}

// Fused GAT attention, 32-row tiles to halve redundant staging.
// grid = 256: t = bid & 63, ib = bid >> 6 (32 output rows). 512 thr = 8 waves
// (2/SIMD), 1 block/CU (LDS ~91 KB). Wave tile = 16 rows x 32 cols.
// __launch_bounds__(512,2) -> 256-VGPR cap (no spill at ~130 live).
__global__ __launch_bounds__(512, 2) void gat_fused(
    const float* __restrict__ A, const float* __restrict__ W,
    const float* __restrict__ b, float* __restrict__ out)
{
    __shared__ unsigned short Ah_s[NN * NN];   // bf16 hi of A[t,f,j]   (32 KB)
    __shared__ unsigned short Al_s[NN * NN];   // bf16 lo residual      (32 KB)
    __shared__ unsigned short ah_s[32 * NN];   // bf16 hi of alpha      (8 KB)
    __shared__ unsigned short al_s[32 * NN];   // bf16 lo residual      (8 KB)
    __shared__ float part1_s[8 * NN];          // per-wave s1 partials  (4 KB)
    __shared__ float part2_s[8 * NN];          // per-wave s2 partials  (4 KB)
    __shared__ float s1_s[NN], s2_s[NN];       // 1 KB

    const int tid  = threadIdx.x;
    const int lane = tid & 63;
    const int wid  = tid >> 6;
    const int t    = blockIdx.x & 63;
    const int i0   = (blockIdx.x >> 6) << 5;   // 32-row tile
    const float* At = A + (size_t)t * NN * NN;

    // ---- stage A[t] -> (hi,lo) bf16 LDS; fused fp32 s1/s2 partial sums ----
    {
        const float4* A4 = reinterpret_cast<const float4*>(At);
        float p1[4] = {0,0,0,0}, p2[4] = {0,0,0,0};
        #pragma unroll
        for (int it = 0; it < 8; ++it) {
            int e4 = it * 512 + tid;          // float4 index 0..4095, coalesced
            int f  = e4 >> 5;                 // A row (k of s1/s2)
            int cs = (e4 & 31) << 2;          // column
            float4 v = A4[e4];
            float w1 = W[f], w2 = W[NN + f];  // wave-uniform broadcast loads
            p1[0] += w1 * v.x; p1[1] += w1 * v.y; p1[2] += w1 * v.z; p1[3] += w1 * v.w;
            p2[0] += w2 * v.x; p2[1] += w2 * v.y; p2[2] += w2 * v.z; p2[3] += w2 * v.w;
            uint2 hv, lv;
            hv.x = pk_hi(v.x, v.y);
            hv.y = pk_hi(v.z, v.w);
            lv.x = pk_hi(resid(v.x), resid(v.y));
            lv.y = pk_hi(resid(v.z), resid(v.w));
            int idx = SWZ(f, cs);
            *reinterpret_cast<uint2*>(&Ah_s[idx]) = hv;
            *reinterpret_cast<uint2*>(&Al_s[idx]) = lv;
        }
        // lane l and l^32 covered disjoint row sets of the same columns
        #pragma unroll
        for (int q = 0; q < 4; ++q) {
            p1[q] += __shfl_xor(p1[q], 32);
            p2[q] += __shfl_xor(p2[q], 32);
        }
        if (lane < 32) {                      // col = lane*4+q
            float4 v1 = { p1[0], p1[1], p1[2], p1[3] };
            float4 v2 = { p2[0], p2[1], p2[2], p2[3] };
            *reinterpret_cast<float4*>(&part1_s[wid * NN + lane * 4]) = v1;
            *reinterpret_cast<float4*>(&part2_s[wid * NN + lane * 4]) = v2;
        }
    }
    __syncthreads();

    // ---- final s1/s2 reduce over the 8 wave partials ----
    if (tid < NN) {
        float s = b[0];
        #pragma unroll
        for (int w = 0; w < 8; ++w) s += part1_s[w * NN + tid];
        s1_s[tid] = s;
    } else if (tid < 2 * NN) {
        int c = tid - NN;
        float s = 0.f;
        #pragma unroll
        for (int w = 0; w < 8; ++w) s += part2_s[w * NN + c];
        s2_s[c] = s;
    }
    __syncthreads();

    // ---- shared softmax for rows i0..i0+31 (16 lanes/row, 8 cols/lane) ----
    {
        int rr = tid >> 4;                    // 0..31 local row
        int jj = tid & 15;                    // cols jj*8 .. jj*8+7
        float s1v = s1_s[i0 + rr];
        float4 sa = *reinterpret_cast<const float4*>(&s2_s[jj * 8]);
        float4 sb = *reinterpret_cast<const float4*>(&s2_s[jj * 8 + 4]);
        float xs[8] = { sa.x, sa.y, sa.z, sa.w, sb.x, sb.y, sb.z, sb.w };
        float ev[8];
        float m = -3.4e38f;
        #pragma unroll
        for (int c = 0; c < 8; ++c) {
            float x = s1v + xs[c];
            x = (x >= 0.f) ? x : 0.2f * x;    // leaky_relu 0.2
            ev[c] = x;
            m = fmaxf(m, x);
        }
        m = fmaxf(m, __shfl_xor(m, 1));
        m = fmaxf(m, __shfl_xor(m, 2));
        m = fmaxf(m, __shfl_xor(m, 4));
        m = fmaxf(m, __shfl_xor(m, 8));
        float s = 0.f;
        #pragma unroll
        for (int c = 0; c < 8; ++c) { ev[c] = __expf(ev[c] - m); s += ev[c]; }
        s += __shfl_xor(s, 1);
        s += __shfl_xor(s, 2);
        s += __shfl_xor(s, 4);
        s += __shfl_xor(s, 8);
        float inv = 1.0f / s;
        unsigned h[4], l[4];
        #pragma unroll
        for (int c = 0; c < 8; c += 2) {
            float v0 = ev[c] * inv, v1 = ev[c + 1] * inv;
            h[c >> 1] = pk_hi(v0, v1);
            l[c >> 1] = pk_hi(resid(v0), resid(v1));
        }
        int idx = SWZ(rr, jj * 8);
        uint4 hv = { h[0], h[1], h[2], h[3] };
        uint4 lv = { l[0], l[1], l[2], l[3] };
        *reinterpret_cast<uint4*>(&ah_s[idx]) = hv;
        *reinterpret_cast<uint4*>(&al_s[idx]) = lv;
    }
    __syncthreads();

    // ---- PV via MFMA: out rows i0+iw*16.., cols f0..f0+31 per wave ----
    {
        const int iw = wid >> 2;              // i sub-tile 0/1
        const int f0 = (wid & 3) << 5;        // wave's 32 output cols
        const int r  = lane & 15;
        const int g  = lane >> 4;             // k sub-group 0..3
        const int kg = g << 3;
        const int arow = (iw << 4) + r;       // alpha local row

        f32x4 acc0 = {0.f,0.f,0.f,0.f}, acc1 = {0.f,0.f,0.f,0.f};
        #pragma unroll
        for (int k0 = 0; k0 < 4; ++k0) {
            int c = k0 * 32 + kg;
            short8 ahk = *reinterpret_cast<const short8*>(&ah_s[SWZ(arow, c)]);
            short8 alk = *reinterpret_cast<const short8*>(&al_s[SWZ(arow, c)]);
            short8 bh0 = *reinterpret_cast<const short8*>(&Ah_s[SWZ(f0 + r, c)]);
            short8 bh1 = *reinterpret_cast<const short8*>(&Ah_s[SWZ(f0 + 16 + r, c)]);
            short8 bl0 = *reinterpret_cast<const short8*>(&Al_s[SWZ(f0 + r, c)]);
            short8 bl1 = *reinterpret_cast<const short8*>(&Al_s[SWZ(f0 + 16 + r, c)]);
            acc0 = __builtin_amdgcn_mfma_f32_16x16x32_bf16(ahk, bh0, acc0, 0, 0, 0);
            acc1 = __builtin_amdgcn_mfma_f32_16x16x32_bf16(ahk, bh1, acc1, 0, 0, 0);
            acc0 = __builtin_amdgcn_mfma_f32_16x16x32_bf16(alk, bh0, acc0, 0, 0, 0);
            acc1 = __builtin_amdgcn_mfma_f32_16x16x32_bf16(alk, bh1, acc1, 0, 0, 0);
            acc0 = __builtin_amdgcn_mfma_f32_16x16x32_bf16(ahk, bl0, acc0, 0, 0, 0);
            acc1 = __builtin_amdgcn_mfma_f32_16x16x32_bf16(ahk, bl1, acc1, 0, 0, 0);
        }

        // C/D: col = lane&15 (f), row = g*4 + q (i)
        float* outt = out + (size_t)t * NN * NN
                    + (size_t)(i0 + (iw << 4) + (g << 2)) * NN;
        #pragma unroll
        for (int q = 0; q < 4; ++q) {
            outt[q * NN + f0 + r]      = acc0[q];
            outt[q * NN + f0 + 16 + r] = acc1[q];
        }
    }
}

extern "C" void kernel_launch(void* const* d_in, const int* in_sizes, int n_in,
                              void* d_out, int out_size, void* d_ws, size_t ws_size,
                              hipStream_t stream) {
    const float* A = (const float*)d_in[0];
    const float* W = (const float*)d_in[1];
    const float* b = (const float*)d_in[2];
    float* out = (float*)d_out;
    gat_fused<<<dim3(256), dim3(512), 0, stream>>>(A, W, b, out);
}